// Round 8
// baseline (1926.057 us; speedup 1.0000x reference)
//
#include <hip/hip_runtime.h>
#include <hip/hip_fp16.h>

#define NNODES 100000
#define NPAD   100032            // 64*1563
#define NEDGES 1600000
#define NBLK_GEMM (NPAD / 64)    // 1563

#define BKT   512                // nodes per bucket
#define NBKT  ((NNODES + BKT - 1) / BKT)   // 196
#define CAP   10240              // real-edge slab capacity (mean 8192)
#define PCAP  18432              // padded slab capacity (CAP + 512*16)
#define EPB   2048               // edges per block, pass A
#define NBLK_A ((NEDGES + EPB - 1) / EPB)
#define NBIN  64                 // nb histogram bins (nb realistically <= 4)

typedef _Float16 half8 __attribute__((ext_vector_type(8)));
typedef float floatx4 __attribute__((ext_vector_type(4)));
typedef int int4v __attribute__((ext_vector_type(4)));

// ---------------- weight shuffle (f32 -> MFMA-B-layout f16) ------------------
template <int C>
__device__ inline void wshuf_one(const float* __restrict__ Ws, const float* __restrict__ Wn,
                                 __half* __restrict__ Wb, int t) {
    constexpr int NCT = 2 * C / 16;
    int lane  = t & 63;
    int ctile = (t >> 6) % NCT;
    int kstep = t / (64 * NCT);
    int n  = ctile * 16 + (lane & 15);
    int k0 = kstep * 32 + (lane >> 4) * 8;
    half8 w8;
#pragma unroll
    for (int j = 0; j < 8; ++j) {
        int k = k0 + j;
        float w = (n < C) ? Ws[k * C + n] : Wn[k * C + (n - C)];
        w8[j] = (_Float16)w;
    }
    ((half8*)Wb)[t] = w8;
}

// ---------------- CSR pass A + fused wshuf -----------------------------------
__global__ __launch_bounds__(256) void k_binA(const int* __restrict__ src, const int* __restrict__ dst,
                                              int* __restrict__ gcur, unsigned* __restrict__ pairs,
                                              const float* __restrict__ Ws0, const float* __restrict__ Wn0, __half* __restrict__ Wb0,
                                              const float* __restrict__ Ws1, const float* __restrict__ Wn1, __half* __restrict__ Wb1,
                                              const float* __restrict__ Ws2, const float* __restrict__ Wn2, __half* __restrict__ Wb2) {
    __shared__ int cnt[NBKT];
    __shared__ int cur[NBKT];
    if (blockIdx.x >= NBLK_A) {
        int wb = blockIdx.x - NBLK_A;
        if (wb < 16)      wshuf_one<128>(Ws0, Wn0, Wb0, wb * 256 + threadIdx.x);
        else if (wb < 32) wshuf_one<128>(Ws1, Wn1, Wb1, (wb - 16) * 256 + threadIdx.x);
        else              wshuf_one<64>(Ws2, Wn2, Wb2, (wb - 32) * 256 + threadIdx.x);
        return;
    }
    int t = threadIdx.x;
    if (t < NBKT) cnt[t] = 0;
    __syncthreads();
    int e0 = blockIdx.x * EPB;
    for (int i = t; i < EPB; i += 256) {
        int e = e0 + i;
        if (e < NEDGES) atomicAdd(&cnt[dst[e] >> 9], 1);
    }
    __syncthreads();
    if (t < NBKT) {
        int c = cnt[t];
        cur[t] = (c > 0) ? atomicAdd(&gcur[t], c) : 0;
    }
    __syncthreads();
    for (int i = t; i < EPB; i += 256) {
        int e = e0 + i;
        if (e < NEDGES) {
            int d = dst[e];
            int b = d >> 9;
            int pos = atomicAdd(&cur[b], 1);
            pairs[b * CAP + pos] = (unsigned)src[e] | ((unsigned)(d & 511) << 20);
        }
    }
}

// ---------------- CSR pass B body + global nb histogram ----------------------
__device__ void binB_body(int b, const unsigned* __restrict__ pairs,
                          const int* __restrict__ gcnt,
                          int* __restrict__ row_ptr, float* __restrict__ deg_inv,
                          int* __restrict__ edge_src, int* __restrict__ nbins) {
    __shared__ int hist[BKT];
    __shared__ int woff[4];
    int t = threadIdx.x;               // 0..255
    int n = gcnt[b];
    int base = b * PCAP;
    const unsigned* pp = pairs + (size_t)b * CAP;
    hist[t] = 0; hist[t + 256] = 0;
    __syncthreads();
    for (int i = t; i < n; i += 256) atomicAdd(&hist[pp[i] >> 20], 1);
    __syncthreads();
    int v0 = hist[2 * t], v1 = hist[2 * t + 1];
    int p0 = (v0 + 15) & ~15, p1 = (v1 + 15) & ~15;
    int tsum = p0 + p1;
    int lane = t & 63;
    int incl = tsum;
#pragma unroll
    for (int off = 1; off < 64; off <<= 1) {
        int u = __shfl_up(incl, off, 64);
        if (lane >= off) incl += u;
    }
    int w = t >> 6;
    if (lane == 63) woff[w] = incl;
    __syncthreads();
    int wo = 0;
#pragma unroll
    for (int i = 0; i < 4; ++i) wo += (i < w) ? woff[i] : 0;
    int excl = wo + incl - tsum;       // exclusive prefix of padded degs
    int pref0 = excl, pref1 = excl + p0;
    int node0 = b * BKT + 2 * t, node1 = node0 + 1;
    if (node0 < NNODES) {
        row_ptr[node0] = (base + pref0) | ((p0 >> 4) << 24);
        deg_inv[node0] = 1.0f / fmaxf((float)v0, 1.0f);
        atomicAdd(&nbins[min(p0 >> 4, NBIN - 1)], 1);
    }
    if (node1 < NNODES) {
        row_ptr[node1] = (base + pref1) | ((p1 >> 4) << 24);
        deg_inv[node1] = 1.0f / fmaxf((float)v1, 1.0f);
        atomicAdd(&nbins[min(p1 >> 4, NBIN - 1)], 1);
    }
    for (int i = v0; i < p0; ++i) edge_src[base + pref0 + i] = NNODES;
    for (int i = v1; i < p1; ++i) edge_src[base + pref1 + i] = NNODES;
    __syncthreads();
    hist[2 * t] = pref0; hist[2 * t + 1] = pref1;   // hist -> scatter cursors
    __syncthreads();
    for (int i = t; i < n; i += 256) {
        unsigned p = pp[i];
        int pos = atomicAdd(&hist[p >> 20], 1);
        edge_src[base + pos] = (int)(p & 0xFFFFF);
    }
}

// ---------------- MFMA GEMM body (layer 0 only), LDS-staged epilogue ---------
__device__ void gemm0_body(int bid, const float* __restrict__ x,
                           const __half* __restrict__ Wb,
                           const float* __restrict__ bias,
                           __half* __restrict__ zs, __half* __restrict__ zn) {
    constexpr int NCT = 16;
    int lane = threadIdx.x & 63;
    int wave = threadIdx.x >> 6;
    int row0 = bid * 64 + wave * 16;
    int m = lane & 15, quad = lane >> 4;
    const half8* Bq = (const half8*)Wb;

    floatx4 acc[NCT];
#pragma unroll
    for (int c = 0; c < NCT; ++c) acc[c] = floatx4{0.f, 0.f, 0.f, 0.f};

    int ar = row0 + m;
    if (ar > NNODES - 1) ar = NNODES - 1;   // clamp: x has exactly NNODES rows

#pragma unroll
    for (int ks = 0; ks < 4; ++ks) {
        half8 a;
        const float* Af = x + (size_t)ar * 128 + quad * 8 + ks * 32;
        floatx4 f0 = *(const floatx4*)(Af);
        floatx4 f1 = *(const floatx4*)(Af + 4);
        a[0] = (_Float16)f0.x; a[1] = (_Float16)f0.y; a[2] = (_Float16)f0.z; a[3] = (_Float16)f0.w;
        a[4] = (_Float16)f1.x; a[5] = (_Float16)f1.y; a[6] = (_Float16)f1.z; a[7] = (_Float16)f1.w;
#pragma unroll
        for (int c = 0; c < NCT; ++c) {
            half8 b = Bq[(size_t)(ks * NCT + c) * 64 + lane];
            acc[c] = __builtin_amdgcn_mfma_f32_16x16x32_f16(a, b, acc[c], 0, 0, 0);
        }
    }

    __shared__ _Float16 st[4][16][264];
#pragma unroll
    for (int c = 0; c < NCT; ++c) {
        bool is_self = (c < NCT / 2);
        int col = c * 16 + m;          // 0..255 (self: 0..127, neigh: 128..255)
        float bv = is_self ? bias[col] : 0.f;
#pragma unroll
        for (int r = 0; r < 4; ++r) st[wave][quad * 4 + r][col] = (_Float16)(acc[c][r] + bv);
    }
#pragma unroll
    for (int p = 0; p < 8; ++p) {
        int idx = p * 64 + lane;
        int row = idx >> 5, ch = idx & 31;
        int grow = row0 + row;
        half8 v = *(const half8*)&st[wave][row][ch * 8];
        if (ch < 16) {
            if (grow < NNODES)
                *(half8*)(zs + (size_t)grow * 128 + ch * 8) = v;
        } else {
            if (grow < NNODES)
                *(half8*)(zn + (size_t)grow * 128 + (ch - 16) * 8) = v;
            else if (grow == NNODES) {
                half8 z;
#pragma unroll
                for (int j = 0; j < 8; ++j) z[j] = (_Float16)0.f;
                *(half8*)(zn + (size_t)grow * 128 + (ch - 16) * 8) = z;
            }
        }
    }
}

// ---------------- fused: binB (blocks 0..NBKT-1) + layer-0 GEMM --------------
__global__ __launch_bounds__(256) void k_binBg0(const unsigned* __restrict__ pairs,
                                                const int* __restrict__ gcnt,
                                                int* __restrict__ row_ptr, float* __restrict__ deg_inv,
                                                int* __restrict__ edge_src, int* __restrict__ nbins,
                                                const float* __restrict__ x,
                                                const __half* __restrict__ Wb0,
                                                const float* __restrict__ b0,
                                                __half* __restrict__ zsA, __half* __restrict__ znA) {
    if (blockIdx.x < NBKT) {
        binB_body(blockIdx.x, pairs, gcnt, row_ptr, deg_inv, edge_src, nbins);
        return;
    }
    gemm0_body(blockIdx.x - NBKT, x, Wb0, b0, zsA, znA);
}

// ---------------- nb-bin exclusive scan (1 block, 64 threads) ----------------
__global__ __launch_bounds__(64) void k_scan(const int* __restrict__ nbins, int* __restrict__ ncur) {
    int t = threadIdx.x;
    int v = nbins[t];
    int incl = v;
#pragma unroll
    for (int off = 1; off < 64; off <<= 1) {
        int u = __shfl_up(incl, off, 64);
        if (t >= off) incl += u;
    }
    ncur[t] = incl - v;
}

// ---------------- build degree-sorted permutation ----------------------------
// R12: counting-sort node ids by nb so every 16-node aggemm block (and every
// gather wave) has uniform batch count -> no exec-mask divergence on the
// gather loop, no __syncthreads straggler. Per-node math unchanged.
__global__ __launch_bounds__(256) void k_mkperm(const int* __restrict__ row_ptr,
                                                int* __restrict__ ncur, int* __restrict__ perm) {
    int node = blockIdx.x * 256 + threadIdx.x;
    if (node < NNODES) {
        int nb = (int)((unsigned)row_ptr[node] >> 24);
        int pos = atomicAdd(&ncur[min(nb, NBIN - 1)], 1);
        perm[pos] = node;
    }
}

// ---------------- fused aggadd(layer L) + GEMM(layer L+1), permuted ----------
template <int COUT>
__global__ __launch_bounds__(256) void k_aggemm(const __half* __restrict__ zn,
                                                const __half* __restrict__ zs,
                                                const int* __restrict__ row_ptr,
                                                const int* __restrict__ edge_src,
                                                const float* __restrict__ deg_inv,
                                                const int* __restrict__ perm,
                                                const __half* __restrict__ Wb,
                                                const float* __restrict__ bias,
                                                void* __restrict__ zs_out,
                                                __half* __restrict__ zn_out) {
    int t = threadIdx.x;
    int lane = t & 63, w = t >> 6;
    int su = lane >> 4, lr = lane & 15;
    int node = perm[blockIdx.x * 16 + w * 4 + su];

    // zn_out sentinel row (read by the NEXT kernel's gather padding)
    if (blockIdx.x == 0 && t < COUT / 8) {
        half8 z;
#pragma unroll
        for (int j = 0; j < 8; ++j) z[j] = (_Float16)0.f;
        *(half8*)(zn_out + (size_t)NNODES * COUT + t * 8) = z;
    }

    // ---- agg phase (C_in = 128) ----
    unsigned rp = (unsigned)row_ptr[node];
    int beg = (int)(rp & 0xFFFFFFu);
    int nb  = (int)(rp >> 24);
    const half8* zb = (const half8*)zn;

    float s[8];
#pragma unroll
    for (int j = 0; j < 8; ++j) s[j] = 0.f;

    for (int b = 0; b < nb; ++b) {
        const int4v* ip = (const int4v*)(edge_src + beg + b * 16);
        int4v i0 = __builtin_nontemporal_load(ip);
        int4v i1 = __builtin_nontemporal_load(ip + 1);
        int4v i2 = __builtin_nontemporal_load(ip + 2);
        int4v i3 = __builtin_nontemporal_load(ip + 3);
        half8 v[16];
        v[0]  = zb[(size_t)i0.x * 16 + lr];
        v[1]  = zb[(size_t)i0.y * 16 + lr];
        v[2]  = zb[(size_t)i0.z * 16 + lr];
        v[3]  = zb[(size_t)i0.w * 16 + lr];
        v[4]  = zb[(size_t)i1.x * 16 + lr];
        v[5]  = zb[(size_t)i1.y * 16 + lr];
        v[6]  = zb[(size_t)i1.z * 16 + lr];
        v[7]  = zb[(size_t)i1.w * 16 + lr];
        v[8]  = zb[(size_t)i2.x * 16 + lr];
        v[9]  = zb[(size_t)i2.y * 16 + lr];
        v[10] = zb[(size_t)i2.z * 16 + lr];
        v[11] = zb[(size_t)i2.w * 16 + lr];
        v[12] = zb[(size_t)i3.x * 16 + lr];
        v[13] = zb[(size_t)i3.y * 16 + lr];
        v[14] = zb[(size_t)i3.z * 16 + lr];
        v[15] = zb[(size_t)i3.w * 16 + lr];
#pragma unroll
        for (int st = 1; st < 16; st <<= 1)
#pragma unroll
            for (int e = 0; e < 16; e += 2 * st) v[e] += v[e + st];
#pragma unroll
        for (int j = 0; j < 8; ++j) s[j] += (float)v[0][j];
    }

    float di = deg_inv[node];
    half8 z = __builtin_nontemporal_load((const half8*)zs + (size_t)node * 16 + lr);
    __shared__ _Float16 At[16][136];
    __shared__ int nid[16];
    if (lr == 0) nid[w * 4 + su] = node;
    half8 h;
#pragma unroll
    for (int j = 0; j < 8; ++j) {
        float o = (float)z[j] + s[j] * di;
        h[j] = (_Float16)fmaxf(o, 0.f);          // ReLU (layers 0,1 both fused)
    }
    *(half8*)&At[w * 4 + su][lr * 8] = h;
    __syncthreads();

    // ---- gemm phase: 16 rows x 2*COUT cols, K=128 ----
    constexpr int NCT = 2 * COUT / 16;   // 16 (COUT=128) or 8 (COUT=64)
    constexpr int CPW = NCT / 4;         // ct per wave: 4 or 2
    int m = lane & 15, quad = lane >> 4;
    const half8* Bq = (const half8*)Wb;

    floatx4 acc[CPW];
#pragma unroll
    for (int cc = 0; cc < CPW; ++cc) acc[cc] = floatx4{0.f, 0.f, 0.f, 0.f};

#pragma unroll
    for (int ks = 0; ks < 4; ++ks) {
        half8 a = *(const half8*)&At[m][quad * 8 + ks * 32];
#pragma unroll
        for (int cc = 0; cc < CPW; ++cc) {
            int c = w * CPW + cc;
            half8 b = Bq[(size_t)(ks * NCT + c) * 64 + lane];
            acc[cc] = __builtin_amdgcn_mfma_f32_16x16x32_f16(a, b, acc[cc], 0, 0, 0);
        }
    }

    if constexpr (COUT == 128) {
        __shared__ _Float16 st2[16][264];
#pragma unroll
        for (int cc = 0; cc < CPW; ++cc) {
            int c = w * CPW + cc;
            bool is_self = (c < 8);
            int col = c * 16 + m;
            float bv = is_self ? bias[col] : 0.f;
#pragma unroll
            for (int r = 0; r < 4; ++r) st2[quad * 4 + r][col] = (_Float16)(acc[cc][r] + bv);
        }
        __syncthreads();
#pragma unroll
        for (int p = 0; p < 2; ++p) {
            int idx = p * 256 + t;
            int row = idx >> 5, ch = idx & 31;
            int grow = nid[row];
            half8 v = *(const half8*)&st2[row][ch * 8];
            if (ch < 16) *(half8*)((__half*)zs_out + (size_t)grow * 128 + ch * 8) = v;
            else         *(half8*)(zn_out + (size_t)grow * 128 + (ch - 16) * 8) = v;
        }
    } else {
        __shared__ float    sts[16][68];
        __shared__ _Float16 stn[16][72];
#pragma unroll
        for (int cc = 0; cc < CPW; ++cc) {
            int c = w * CPW + cc;
            bool is_self = (c < 4);
            if (is_self) {
                int col = c * 16 + m;
                float bv = bias[col];
#pragma unroll
                for (int r = 0; r < 4; ++r) sts[quad * 4 + r][col] = acc[cc][r] + bv;
            } else {
                int col = (c - 4) * 16 + m;
#pragma unroll
                for (int r = 0; r < 4; ++r) stn[quad * 4 + r][col] = (_Float16)acc[cc][r];
            }
        }
        __syncthreads();
        {
            int row = t >> 4, ch = t & 15;
            int grow = nid[row];
            *((floatx4*)zs_out + (size_t)grow * 16 + ch) = *(const floatx4*)&sts[row][ch * 4];
        }
        if (t < 128) {
            int row = t >> 3, ch = t & 7;
            int grow = nid[row];
            *(half8*)(zn_out + (size_t)grow * 64 + ch * 8) = *(const half8*)&stn[row][ch * 8];
        }
    }
}

// ---------------- final gather-add (layer 2, C=64, f32 out), permuted --------
__global__ __launch_bounds__(256) void k_aggfin(const __half* __restrict__ zn,
                                                const float* __restrict__ zs,
                                                const int* __restrict__ row_ptr,
                                                const int* __restrict__ edge_src,
                                                const float* __restrict__ deg_inv,
                                                const int* __restrict__ perm,
                                                float* __restrict__ outv) {
    constexpr int LPR  = 8;              // lanes per node-row
    constexpr int NSUB = 8;              // nodes per wave
    constexpr int NPB  = 32;             // nodes per block
    int lane = threadIdx.x & 63;
    int su = lane / LPR;
    int lr = lane % LPR;
    int node = perm[blockIdx.x * NPB + (threadIdx.x >> 6) * NSUB + su];
    unsigned rp = (unsigned)row_ptr[node];
    int beg = (int)(rp & 0xFFFFFFu);
    int nb  = (int)(rp >> 24);
    const half8* zb = (const half8*)zn;

    float s[8];
#pragma unroll
    for (int j = 0; j < 8; ++j) s[j] = 0.f;

    for (int b = 0; b < nb; ++b) {
        const int4v* ip = (const int4v*)(edge_src + beg + b * 16);
        int4v i0 = __builtin_nontemporal_load(ip);
        int4v i1 = __builtin_nontemporal_load(ip + 1);
        half8 v[16];
        v[0]  = zb[(size_t)i0.x * LPR + lr];
        v[1]  = zb[(size_t)i0.y * LPR + lr];
        v[2]  = zb[(size_t)i0.z * LPR + lr];
        v[3]  = zb[(size_t)i0.w * LPR + lr];
        v[4]  = zb[(size_t)i1.x * LPR + lr];
        v[5]  = zb[(size_t)i1.y * LPR + lr];
        v[6]  = zb[(size_t)i1.z * LPR + lr];
        v[7]  = zb[(size_t)i1.w * LPR + lr];
        const int4v* ip2 = ip + 2;
        int4v i2 = __builtin_nontemporal_load(ip2);
        int4v i3 = __builtin_nontemporal_load(ip2 + 1);
        v[8]  = zb[(size_t)i2.x * LPR + lr];
        v[9]  = zb[(size_t)i2.y * LPR + lr];
        v[10] = zb[(size_t)i2.z * LPR + lr];
        v[11] = zb[(size_t)i2.w * LPR + lr];
        v[12] = zb[(size_t)i3.x * LPR + lr];
        v[13] = zb[(size_t)i3.y * LPR + lr];
        v[14] = zb[(size_t)i3.z * LPR + lr];
        v[15] = zb[(size_t)i3.w * LPR + lr];
#pragma unroll
        for (int st = 1; st < 16; st <<= 1)
#pragma unroll
            for (int e = 0; e < 16; e += 2 * st) v[e] += v[e + st];
#pragma unroll
        for (int j = 0; j < 8; ++j) s[j] += (float)v[0][j];
    }

    float di = deg_inv[node];
    const floatx4* zp = (const floatx4*)zs + (size_t)node * 16 + lr * 2;
    floatx4 z0 = __builtin_nontemporal_load(zp);
    floatx4 z1 = __builtin_nontemporal_load(zp + 1);
    float o[8];
    o[0] = z0.x + s[0] * di; o[1] = z0.y + s[1] * di;
    o[2] = z0.z + s[2] * di; o[3] = z0.w + s[3] * di;
    o[4] = z1.x + s[4] * di; o[5] = z1.y + s[5] * di;
    o[6] = z1.z + s[6] * di; o[7] = z1.w + s[7] * di;
    floatx4* op = (floatx4*)outv + (size_t)node * 16 + lr * 2;
    __builtin_nontemporal_store(floatx4{o[0], o[1], o[2], o[3]}, op);
    __builtin_nontemporal_store(floatx4{o[4], o[5], o[6], o[7]}, op + 1);
}

// ---------------- launch ----------------

extern "C" void kernel_launch(void* const* d_in, const int* in_sizes, int n_in,
                              void* d_out, int out_size, void* d_ws, size_t ws_size,
                              hipStream_t stream) {
    const float* x   = (const float*)d_in[0];
    const int*   src = (const int*)d_in[1];
    const int*   dst = (const int*)d_in[2];
    const float* Ws0 = (const float*)d_in[3];
    const float* Wn0 = (const float*)d_in[4];
    const float* b0  = (const float*)d_in[5];
    const float* Ws1 = (const float*)d_in[6];
    const float* Wn1 = (const float*)d_in[7];
    const float* b1  = (const float*)d_in[8];
    const float* Ws2 = (const float*)d_in[9];
    const float* Wn2 = (const float*)d_in[10];
    const float* b2  = (const float*)d_in[11];
    float* out = (float*)d_out;

    char* ws = (char*)d_ws;
    size_t off = 0;
    auto alloc = [&](size_t bytes) -> void* {
        off = (off + 255) & ~(size_t)255;
        void* p = ws + off;
        off += bytes;
        return p;
    };
    int*      row_ptr  = (int*)alloc((size_t)NNODES * 4);
    float*    deg_inv  = (float*)alloc((size_t)NNODES * 4);
    int*      perm     = (int*)alloc((size_t)NNODES * 4);
    int*      edge_src = (int*)alloc((size_t)NBKT * PCAP * 4);
    int*      aux      = (int*)alloc((size_t)(NBKT + 2 * NBIN) * 4);  // gcur | nbins | ncur
    unsigned* pairs    = (unsigned*)alloc((size_t)NBKT * CAP * 4);
    __half*   zsA      = (__half*)alloc((size_t)NPAD * 128 * 2);
    __half*   znA      = (__half*)alloc((size_t)NPAD * 128 * 2);
    __half*   zsB      = (__half*)alloc((size_t)NPAD * 128 * 2);
    __half*   znB      = (__half*)alloc((size_t)NPAD * 128 * 2);
    float*    zs32     = (float*)alloc((size_t)NNODES * 64 * 4);
    __half*   zn64     = (__half*)alloc((size_t)NPAD * 64 * 2);
    __half*   Wb0      = (__half*)alloc((size_t)4 * 16 * 64 * 8 * 2);
    __half*   Wb1      = (__half*)alloc((size_t)4 * 16 * 64 * 8 * 2);
    __half*   Wb2      = (__half*)alloc((size_t)4 * 8 * 64 * 8 * 2);
    int* gcur  = aux;
    int* nbins = aux + NBKT;
    int* ncur  = aux + NBKT + NBIN;
    (void)ws_size; (void)n_in; (void)in_sizes; (void)out_size;

    // CSR pass A (+ wshuf in extra blocks)
    hipMemsetAsync(aux, 0, (size_t)(NBKT + 2 * NBIN) * 4, stream);
    k_binA<<<NBLK_A + 40, 256, 0, stream>>>(src, dst, gcur, pairs,
                                            Ws0, Wn0, Wb0, Ws1, Wn1, Wb1, Ws2, Wn2, Wb2);
    // CSR pass B (+ nb histogram) fused with layer-0 GEMM
    k_binBg0<<<NBKT + NBLK_GEMM, 256, 0, stream>>>(pairs, gcur, row_ptr, deg_inv, edge_src, nbins,
                                                   x, Wb0, b0, zsA, znA);
    // degree-sorted permutation
    k_scan<<<1, 64, 0, stream>>>(nbins, ncur);
    k_mkperm<<<(NNODES + 255) / 256, 256, 0, stream>>>(row_ptr, ncur, perm);
    // agg layer 0 + GEMM layer 1 (fused; no h1 roundtrip)
    k_aggemm<128><<<NNODES / 16, 256, 0, stream>>>(znA, zsA, row_ptr, edge_src, deg_inv, perm,
                                                   Wb1, b1, zsB, znB);
    // agg layer 1 + GEMM layer 2 (fused; no h2 roundtrip)
    k_aggemm<64><<<NNODES / 16, 256, 0, stream>>>(znB, zsB, row_ptr, edge_src, deg_inv, perm,
                                                  Wb2, b2, zs32, zn64);
    // final agg layer 2 -> out (f32)
    k_aggfin<<<NNODES / 32, 256, 0, stream>>>(zn64, zs32, row_ptr, edge_src, deg_inv, perm, out);
}

// Round 9
// 385.819 us; speedup vs baseline: 4.9921x; 4.9921x over previous
//
#include <hip/hip_runtime.h>
#include <hip/hip_fp16.h>

#define NNODES 100000
#define NPAD   100032            // 64*1563
#define NEDGES 1600000
#define NBLK_GEMM (NPAD / 64)    // 1563

#define BKT   512                // nodes per bucket
#define NBKT  ((NNODES + BKT - 1) / BKT)   // 196
#define CAP   10240              // real-edge slab capacity (mean 8192)
#define PCAP  18432              // padded slab capacity (CAP + 512*16)
#define EPB   2048               // edges per block, pass A
#define NBLK_A ((NEDGES + EPB - 1) / EPB)
#define NBIN  64                 // nb histogram bins (nb realistically <= 4)

typedef _Float16 half8 __attribute__((ext_vector_type(8)));
typedef float floatx4 __attribute__((ext_vector_type(4)));
typedef int int4v __attribute__((ext_vector_type(4)));

// ---------------- weight shuffle (f32 -> MFMA-B-layout f16) ------------------
template <int C>
__device__ inline void wshuf_one(const float* __restrict__ Ws, const float* __restrict__ Wn,
                                 __half* __restrict__ Wb, int t) {
    constexpr int NCT = 2 * C / 16;
    int lane  = t & 63;
    int ctile = (t >> 6) % NCT;
    int kstep = t / (64 * NCT);
    int n  = ctile * 16 + (lane & 15);
    int k0 = kstep * 32 + (lane >> 4) * 8;
    half8 w8;
#pragma unroll
    for (int j = 0; j < 8; ++j) {
        int k = k0 + j;
        float w = (n < C) ? Ws[k * C + n] : Wn[k * C + (n - C)];
        w8[j] = (_Float16)w;
    }
    ((half8*)Wb)[t] = w8;
}

// ---------------- CSR pass A + fused wshuf -----------------------------------
__global__ __launch_bounds__(256) void k_binA(const int* __restrict__ src, const int* __restrict__ dst,
                                              int* __restrict__ gcur, unsigned* __restrict__ pairs,
                                              const float* __restrict__ Ws0, const float* __restrict__ Wn0, __half* __restrict__ Wb0,
                                              const float* __restrict__ Ws1, const float* __restrict__ Wn1, __half* __restrict__ Wb1,
                                              const float* __restrict__ Ws2, const float* __restrict__ Wn2, __half* __restrict__ Wb2) {
    __shared__ int cnt[NBKT];
    __shared__ int cur[NBKT];
    if (blockIdx.x >= NBLK_A) {
        int wb = blockIdx.x - NBLK_A;
        if (wb < 16)      wshuf_one<128>(Ws0, Wn0, Wb0, wb * 256 + threadIdx.x);
        else if (wb < 32) wshuf_one<128>(Ws1, Wn1, Wb1, (wb - 16) * 256 + threadIdx.x);
        else              wshuf_one<64>(Ws2, Wn2, Wb2, (wb - 32) * 256 + threadIdx.x);
        return;
    }
    int t = threadIdx.x;
    if (t < NBKT) cnt[t] = 0;
    __syncthreads();
    int e0 = blockIdx.x * EPB;
    for (int i = t; i < EPB; i += 256) {
        int e = e0 + i;
        if (e < NEDGES) atomicAdd(&cnt[dst[e] >> 9], 1);
    }
    __syncthreads();
    if (t < NBKT) {
        int c = cnt[t];
        cur[t] = (c > 0) ? atomicAdd(&gcur[t], c) : 0;
    }
    __syncthreads();
    for (int i = t; i < EPB; i += 256) {
        int e = e0 + i;
        if (e < NEDGES) {
            int d = dst[e];
            int b = d >> 9;
            int pos = atomicAdd(&cur[b], 1);
            pairs[b * CAP + pos] = (unsigned)src[e] | ((unsigned)(d & 511) << 20);
        }
    }
}

// ---------------- CSR pass B body + LDS-aggregated nb histogram --------------
// R13: nbins via per-block LDS histogram + one global atomic per bin per block
// (R8's per-node global atomics onto ~3 hot addresses serialized ~800us).
__device__ void binB_body(int b, const unsigned* __restrict__ pairs,
                          const int* __restrict__ gcnt,
                          int* __restrict__ row_ptr, float* __restrict__ deg_inv,
                          int* __restrict__ edge_src, int* __restrict__ nbins) {
    __shared__ int hist[BKT];
    __shared__ int woff[4];
    __shared__ int lbin[NBIN];
    int t = threadIdx.x;               // 0..255
    int n = gcnt[b];
    int base = b * PCAP;
    const unsigned* pp = pairs + (size_t)b * CAP;
    hist[t] = 0; hist[t + 256] = 0;
    if (t < NBIN) lbin[t] = 0;
    __syncthreads();
    for (int i = t; i < n; i += 256) atomicAdd(&hist[pp[i] >> 20], 1);
    __syncthreads();
    int v0 = hist[2 * t], v1 = hist[2 * t + 1];
    int p0 = (v0 + 15) & ~15, p1 = (v1 + 15) & ~15;
    int tsum = p0 + p1;
    int lane = t & 63;
    int incl = tsum;
#pragma unroll
    for (int off = 1; off < 64; off <<= 1) {
        int u = __shfl_up(incl, off, 64);
        if (lane >= off) incl += u;
    }
    int w = t >> 6;
    if (lane == 63) woff[w] = incl;
    __syncthreads();
    int wo = 0;
#pragma unroll
    for (int i = 0; i < 4; ++i) wo += (i < w) ? woff[i] : 0;
    int excl = wo + incl - tsum;       // exclusive prefix of padded degs
    int pref0 = excl, pref1 = excl + p0;
    int node0 = b * BKT + 2 * t, node1 = node0 + 1;
    if (node0 < NNODES) {
        row_ptr[node0] = (base + pref0) | ((p0 >> 4) << 24);
        deg_inv[node0] = 1.0f / fmaxf((float)v0, 1.0f);
        atomicAdd(&lbin[min(p0 >> 4, NBIN - 1)], 1);
    }
    if (node1 < NNODES) {
        row_ptr[node1] = (base + pref1) | ((p1 >> 4) << 24);
        deg_inv[node1] = 1.0f / fmaxf((float)v1, 1.0f);
        atomicAdd(&lbin[min(p1 >> 4, NBIN - 1)], 1);
    }
    for (int i = v0; i < p0; ++i) edge_src[base + pref0 + i] = NNODES;
    for (int i = v1; i < p1; ++i) edge_src[base + pref1 + i] = NNODES;
    __syncthreads();
    if (t < NBIN && lbin[t] > 0) atomicAdd(&nbins[t], lbin[t]);
    hist[2 * t] = pref0; hist[2 * t + 1] = pref1;   // hist -> scatter cursors
    __syncthreads();
    for (int i = t; i < n; i += 256) {
        unsigned p = pp[i];
        int pos = atomicAdd(&hist[p >> 20], 1);
        edge_src[base + pos] = (int)(p & 0xFFFFF);
    }
}

// ---------------- MFMA GEMM body (layer 0 only), LDS-staged epilogue ---------
__device__ void gemm0_body(int bid, const float* __restrict__ x,
                           const __half* __restrict__ Wb,
                           const float* __restrict__ bias,
                           __half* __restrict__ zs, __half* __restrict__ zn) {
    constexpr int NCT = 16;
    int lane = threadIdx.x & 63;
    int wave = threadIdx.x >> 6;
    int row0 = bid * 64 + wave * 16;
    int m = lane & 15, quad = lane >> 4;
    const half8* Bq = (const half8*)Wb;

    floatx4 acc[NCT];
#pragma unroll
    for (int c = 0; c < NCT; ++c) acc[c] = floatx4{0.f, 0.f, 0.f, 0.f};

    int ar = row0 + m;
    if (ar > NNODES - 1) ar = NNODES - 1;   // clamp: x has exactly NNODES rows

#pragma unroll
    for (int ks = 0; ks < 4; ++ks) {
        half8 a;
        const float* Af = x + (size_t)ar * 128 + quad * 8 + ks * 32;
        floatx4 f0 = *(const floatx4*)(Af);
        floatx4 f1 = *(const floatx4*)(Af + 4);
        a[0] = (_Float16)f0.x; a[1] = (_Float16)f0.y; a[2] = (_Float16)f0.z; a[3] = (_Float16)f0.w;
        a[4] = (_Float16)f1.x; a[5] = (_Float16)f1.y; a[6] = (_Float16)f1.z; a[7] = (_Float16)f1.w;
#pragma unroll
        for (int c = 0; c < NCT; ++c) {
            half8 b = Bq[(size_t)(ks * NCT + c) * 64 + lane];
            acc[c] = __builtin_amdgcn_mfma_f32_16x16x32_f16(a, b, acc[c], 0, 0, 0);
        }
    }

    __shared__ _Float16 st[4][16][264];
#pragma unroll
    for (int c = 0; c < NCT; ++c) {
        bool is_self = (c < NCT / 2);
        int col = c * 16 + m;          // 0..255 (self: 0..127, neigh: 128..255)
        float bv = is_self ? bias[col] : 0.f;
#pragma unroll
        for (int r = 0; r < 4; ++r) st[wave][quad * 4 + r][col] = (_Float16)(acc[c][r] + bv);
    }
#pragma unroll
    for (int p = 0; p < 8; ++p) {
        int idx = p * 64 + lane;
        int row = idx >> 5, ch = idx & 31;
        int grow = row0 + row;
        half8 v = *(const half8*)&st[wave][row][ch * 8];
        if (ch < 16) {
            if (grow < NNODES)
                *(half8*)(zs + (size_t)grow * 128 + ch * 8) = v;
        } else {
            if (grow < NNODES)
                *(half8*)(zn + (size_t)grow * 128 + (ch - 16) * 8) = v;
            else if (grow == NNODES) {
                half8 z;
#pragma unroll
                for (int j = 0; j < 8; ++j) z[j] = (_Float16)0.f;
                *(half8*)(zn + (size_t)grow * 128 + (ch - 16) * 8) = z;
            }
        }
    }
}

// ---------------- fused: binB (blocks 0..NBKT-1) + layer-0 GEMM --------------
__global__ __launch_bounds__(256) void k_binBg0(const unsigned* __restrict__ pairs,
                                                const int* __restrict__ gcnt,
                                                int* __restrict__ row_ptr, float* __restrict__ deg_inv,
                                                int* __restrict__ edge_src, int* __restrict__ nbins,
                                                const float* __restrict__ x,
                                                const __half* __restrict__ Wb0,
                                                const float* __restrict__ b0,
                                                __half* __restrict__ zsA, __half* __restrict__ znA) {
    if (blockIdx.x < NBKT) {
        binB_body(blockIdx.x, pairs, gcnt, row_ptr, deg_inv, edge_src, nbins);
        return;
    }
    gemm0_body(blockIdx.x - NBKT, x, Wb0, b0, zsA, znA);
}

// ---------------- nb-bin exclusive scan (1 block, 64 threads) ----------------
__global__ __launch_bounds__(64) void k_scan(const int* __restrict__ nbins, int* __restrict__ ncur) {
    int t = threadIdx.x;
    int v = nbins[t];
    int incl = v;
#pragma unroll
    for (int off = 1; off < 64; off <<= 1) {
        int u = __shfl_up(incl, off, 64);
        if (t >= off) incl += u;
    }
    ncur[t] = incl - v;
}

// ---------------- build degree-sorted permutation (LDS-aggregated) -----------
// R13: per-block LDS counts + ONE global atomic per (block,bin) to reserve a
// range, then local scatter. (R8's per-node global atomics serialized ~700us.)
__global__ __launch_bounds__(256) void k_mkperm(const int* __restrict__ row_ptr,
                                                int* __restrict__ ncur, int* __restrict__ perm) {
    __shared__ int lcnt[NBIN];
    __shared__ int lbase[NBIN];
    int t = threadIdx.x;
    if (t < NBIN) lcnt[t] = 0;
    __syncthreads();
    int node = blockIdx.x * 256 + t;
    int bin = 0, lpos = 0;
    if (node < NNODES) {
        bin = min((int)((unsigned)row_ptr[node] >> 24), NBIN - 1);
        lpos = atomicAdd(&lcnt[bin], 1);
    }
    __syncthreads();
    if (t < NBIN && lcnt[t] > 0) lbase[t] = atomicAdd(&ncur[t], lcnt[t]);
    __syncthreads();
    if (node < NNODES) perm[lbase[bin] + lpos] = node;
}

// ---------------- fused aggadd(layer L) + GEMM(layer L+1), permuted ----------
template <int COUT>
__global__ __launch_bounds__(256) void k_aggemm(const __half* __restrict__ zn,
                                                const __half* __restrict__ zs,
                                                const int* __restrict__ row_ptr,
                                                const int* __restrict__ edge_src,
                                                const float* __restrict__ deg_inv,
                                                const int* __restrict__ perm,
                                                const __half* __restrict__ Wb,
                                                const float* __restrict__ bias,
                                                void* __restrict__ zs_out,
                                                __half* __restrict__ zn_out) {
    int t = threadIdx.x;
    int lane = t & 63, w = t >> 6;
    int su = lane >> 4, lr = lane & 15;
    int node = perm[blockIdx.x * 16 + w * 4 + su];

    // zn_out sentinel row (read by the NEXT kernel's gather padding)
    if (blockIdx.x == 0 && t < COUT / 8) {
        half8 z;
#pragma unroll
        for (int j = 0; j < 8; ++j) z[j] = (_Float16)0.f;
        *(half8*)(zn_out + (size_t)NNODES * COUT + t * 8) = z;
    }

    // ---- agg phase (C_in = 128) ----
    unsigned rp = (unsigned)row_ptr[node];
    int beg = (int)(rp & 0xFFFFFFu);
    int nb  = (int)(rp >> 24);
    const half8* zb = (const half8*)zn;

    float s[8];
#pragma unroll
    for (int j = 0; j < 8; ++j) s[j] = 0.f;

    for (int b = 0; b < nb; ++b) {
        const int4v* ip = (const int4v*)(edge_src + beg + b * 16);
        int4v i0 = __builtin_nontemporal_load(ip);
        int4v i1 = __builtin_nontemporal_load(ip + 1);
        int4v i2 = __builtin_nontemporal_load(ip + 2);
        int4v i3 = __builtin_nontemporal_load(ip + 3);
        half8 v[16];
        v[0]  = zb[(size_t)i0.x * 16 + lr];
        v[1]  = zb[(size_t)i0.y * 16 + lr];
        v[2]  = zb[(size_t)i0.z * 16 + lr];
        v[3]  = zb[(size_t)i0.w * 16 + lr];
        v[4]  = zb[(size_t)i1.x * 16 + lr];
        v[5]  = zb[(size_t)i1.y * 16 + lr];
        v[6]  = zb[(size_t)i1.z * 16 + lr];
        v[7]  = zb[(size_t)i1.w * 16 + lr];
        v[8]  = zb[(size_t)i2.x * 16 + lr];
        v[9]  = zb[(size_t)i2.y * 16 + lr];
        v[10] = zb[(size_t)i2.z * 16 + lr];
        v[11] = zb[(size_t)i2.w * 16 + lr];
        v[12] = zb[(size_t)i3.x * 16 + lr];
        v[13] = zb[(size_t)i3.y * 16 + lr];
        v[14] = zb[(size_t)i3.z * 16 + lr];
        v[15] = zb[(size_t)i3.w * 16 + lr];
#pragma unroll
        for (int st = 1; st < 16; st <<= 1)
#pragma unroll
            for (int e = 0; e < 16; e += 2 * st) v[e] += v[e + st];
#pragma unroll
        for (int j = 0; j < 8; ++j) s[j] += (float)v[0][j];
    }

    float di = deg_inv[node];
    half8 z = __builtin_nontemporal_load((const half8*)zs + (size_t)node * 16 + lr);
    __shared__ _Float16 At[16][136];
    __shared__ int nid[16];
    if (lr == 0) nid[w * 4 + su] = node;
    half8 h;
#pragma unroll
    for (int j = 0; j < 8; ++j) {
        float o = (float)z[j] + s[j] * di;
        h[j] = (_Float16)fmaxf(o, 0.f);          // ReLU (layers 0,1 both fused)
    }
    *(half8*)&At[w * 4 + su][lr * 8] = h;
    __syncthreads();

    // ---- gemm phase: 16 rows x 2*COUT cols, K=128 ----
    constexpr int NCT = 2 * COUT / 16;   // 16 (COUT=128) or 8 (COUT=64)
    constexpr int CPW = NCT / 4;         // ct per wave: 4 or 2
    int m = lane & 15, quad = lane >> 4;
    const half8* Bq = (const half8*)Wb;

    floatx4 acc[CPW];
#pragma unroll
    for (int cc = 0; cc < CPW; ++cc) acc[cc] = floatx4{0.f, 0.f, 0.f, 0.f};

#pragma unroll
    for (int ks = 0; ks < 4; ++ks) {
        half8 a = *(const half8*)&At[m][quad * 8 + ks * 32];
#pragma unroll
        for (int cc = 0; cc < CPW; ++cc) {
            int c = w * CPW + cc;
            half8 b = Bq[(size_t)(ks * NCT + c) * 64 + lane];
            acc[cc] = __builtin_amdgcn_mfma_f32_16x16x32_f16(a, b, acc[cc], 0, 0, 0);
        }
    }

    if constexpr (COUT == 128) {
        __shared__ _Float16 st2[16][264];
#pragma unroll
        for (int cc = 0; cc < CPW; ++cc) {
            int c = w * CPW + cc;
            bool is_self = (c < 8);
            int col = c * 16 + m;
            float bv = is_self ? bias[col] : 0.f;
#pragma unroll
            for (int r = 0; r < 4; ++r) st2[quad * 4 + r][col] = (_Float16)(acc[cc][r] + bv);
        }
        __syncthreads();
#pragma unroll
        for (int p = 0; p < 2; ++p) {
            int idx = p * 256 + t;
            int row = idx >> 5, ch = idx & 31;
            int grow = nid[row];
            half8 v = *(const half8*)&st2[row][ch * 8];
            if (ch < 16) *(half8*)((__half*)zs_out + (size_t)grow * 128 + ch * 8) = v;
            else         *(half8*)(zn_out + (size_t)grow * 128 + (ch - 16) * 8) = v;
        }
    } else {
        __shared__ float    sts[16][68];
        __shared__ _Float16 stn[16][72];
#pragma unroll
        for (int cc = 0; cc < CPW; ++cc) {
            int c = w * CPW + cc;
            bool is_self = (c < 4);
            if (is_self) {
                int col = c * 16 + m;
                float bv = bias[col];
#pragma unroll
                for (int r = 0; r < 4; ++r) sts[quad * 4 + r][col] = acc[cc][r] + bv;
            } else {
                int col = (c - 4) * 16 + m;
#pragma unroll
                for (int r = 0; r < 4; ++r) stn[quad * 4 + r][col] = (_Float16)acc[cc][r];
            }
        }
        __syncthreads();
        {
            int row = t >> 4, ch = t & 15;
            int grow = nid[row];
            *((floatx4*)zs_out + (size_t)grow * 16 + ch) = *(const floatx4*)&sts[row][ch * 4];
        }
        if (t < 128) {
            int row = t >> 3, ch = t & 7;
            int grow = nid[row];
            *(half8*)(zn_out + (size_t)grow * 64 + ch * 8) = *(const half8*)&stn[row][ch * 8];
        }
    }
}

// ---------------- final gather-add (layer 2, C=64, f32 out), permuted --------
__global__ __launch_bounds__(256) void k_aggfin(const __half* __restrict__ zn,
                                                const float* __restrict__ zs,
                                                const int* __restrict__ row_ptr,
                                                const int* __restrict__ edge_src,
                                                const float* __restrict__ deg_inv,
                                                const int* __restrict__ perm,
                                                float* __restrict__ outv) {
    constexpr int LPR  = 8;              // lanes per node-row
    constexpr int NSUB = 8;              // nodes per wave
    constexpr int NPB  = 32;             // nodes per block
    int lane = threadIdx.x & 63;
    int su = lane / LPR;
    int lr = lane % LPR;
    int node = perm[blockIdx.x * NPB + (threadIdx.x >> 6) * NSUB + su];
    unsigned rp = (unsigned)row_ptr[node];
    int beg = (int)(rp & 0xFFFFFFu);
    int nb  = (int)(rp >> 24);
    const half8* zb = (const half8*)zn;

    float s[8];
#pragma unroll
    for (int j = 0; j < 8; ++j) s[j] = 0.f;

    for (int b = 0; b < nb; ++b) {
        const int4v* ip = (const int4v*)(edge_src + beg + b * 16);
        int4v i0 = __builtin_nontemporal_load(ip);
        int4v i1 = __builtin_nontemporal_load(ip + 1);
        half8 v[16];
        v[0]  = zb[(size_t)i0.x * LPR + lr];
        v[1]  = zb[(size_t)i0.y * LPR + lr];
        v[2]  = zb[(size_t)i0.z * LPR + lr];
        v[3]  = zb[(size_t)i0.w * LPR + lr];
        v[4]  = zb[(size_t)i1.x * LPR + lr];
        v[5]  = zb[(size_t)i1.y * LPR + lr];
        v[6]  = zb[(size_t)i1.z * LPR + lr];
        v[7]  = zb[(size_t)i1.w * LPR + lr];
        const int4v* ip2 = ip + 2;
        int4v i2 = __builtin_nontemporal_load(ip2);
        int4v i3 = __builtin_nontemporal_load(ip2 + 1);
        v[8]  = zb[(size_t)i2.x * LPR + lr];
        v[9]  = zb[(size_t)i2.y * LPR + lr];
        v[10] = zb[(size_t)i2.z * LPR + lr];
        v[11] = zb[(size_t)i2.w * LPR + lr];
        v[12] = zb[(size_t)i3.x * LPR + lr];
        v[13] = zb[(size_t)i3.y * LPR + lr];
        v[14] = zb[(size_t)i3.z * LPR + lr];
        v[15] = zb[(size_t)i3.w * LPR + lr];
#pragma unroll
        for (int st = 1; st < 16; st <<= 1)
#pragma unroll
            for (int e = 0; e < 16; e += 2 * st) v[e] += v[e + st];
#pragma unroll
        for (int j = 0; j < 8; ++j) s[j] += (float)v[0][j];
    }

    float di = deg_inv[node];
    const floatx4* zp = (const floatx4*)zs + (size_t)node * 16 + lr * 2;
    floatx4 z0 = __builtin_nontemporal_load(zp);
    floatx4 z1 = __builtin_nontemporal_load(zp + 1);
    float o[8];
    o[0] = z0.x + s[0] * di; o[1] = z0.y + s[1] * di;
    o[2] = z0.z + s[2] * di; o[3] = z0.w + s[3] * di;
    o[4] = z1.x + s[4] * di; o[5] = z1.y + s[5] * di;
    o[6] = z1.z + s[6] * di; o[7] = z1.w + s[7] * di;
    floatx4* op = (floatx4*)outv + (size_t)node * 16 + lr * 2;
    __builtin_nontemporal_store(floatx4{o[0], o[1], o[2], o[3]}, op);
    __builtin_nontemporal_store(floatx4{o[4], o[5], o[6], o[7]}, op + 1);
}

// ---------------- launch ----------------

extern "C" void kernel_launch(void* const* d_in, const int* in_sizes, int n_in,
                              void* d_out, int out_size, void* d_ws, size_t ws_size,
                              hipStream_t stream) {
    const float* x   = (const float*)d_in[0];
    const int*   src = (const int*)d_in[1];
    const int*   dst = (const int*)d_in[2];
    const float* Ws0 = (const float*)d_in[3];
    const float* Wn0 = (const float*)d_in[4];
    const float* b0  = (const float*)d_in[5];
    const float* Ws1 = (const float*)d_in[6];
    const float* Wn1 = (const float*)d_in[7];
    const float* b1  = (const float*)d_in[8];
    const float* Ws2 = (const float*)d_in[9];
    const float* Wn2 = (const float*)d_in[10];
    const float* b2  = (const float*)d_in[11];
    float* out = (float*)d_out;

    char* ws = (char*)d_ws;
    size_t off = 0;
    auto alloc = [&](size_t bytes) -> void* {
        off = (off + 255) & ~(size_t)255;
        void* p = ws + off;
        off += bytes;
        return p;
    };
    int*      row_ptr  = (int*)alloc((size_t)NNODES * 4);
    float*    deg_inv  = (float*)alloc((size_t)NNODES * 4);
    int*      perm     = (int*)alloc((size_t)NNODES * 4);
    int*      edge_src = (int*)alloc((size_t)NBKT * PCAP * 4);
    int*      aux      = (int*)alloc((size_t)(NBKT + 2 * NBIN) * 4);  // gcur | nbins | ncur
    unsigned* pairs    = (unsigned*)alloc((size_t)NBKT * CAP * 4);
    __half*   zsA      = (__half*)alloc((size_t)NPAD * 128 * 2);
    __half*   znA      = (__half*)alloc((size_t)NPAD * 128 * 2);
    __half*   zsB      = (__half*)alloc((size_t)NPAD * 128 * 2);
    __half*   znB      = (__half*)alloc((size_t)NPAD * 128 * 2);
    float*    zs32     = (float*)alloc((size_t)NNODES * 64 * 4);
    __half*   zn64     = (__half*)alloc((size_t)NPAD * 64 * 2);
    __half*   Wb0      = (__half*)alloc((size_t)4 * 16 * 64 * 8 * 2);
    __half*   Wb1      = (__half*)alloc((size_t)4 * 16 * 64 * 8 * 2);
    __half*   Wb2      = (__half*)alloc((size_t)4 * 8 * 64 * 8 * 2);
    int* gcur  = aux;
    int* nbins = aux + NBKT;
    int* ncur  = aux + NBKT + NBIN;
    (void)ws_size; (void)n_in; (void)in_sizes; (void)out_size;

    // CSR pass A (+ wshuf in extra blocks)
    hipMemsetAsync(aux, 0, (size_t)(NBKT + 2 * NBIN) * 4, stream);
    k_binA<<<NBLK_A + 40, 256, 0, stream>>>(src, dst, gcur, pairs,
                                            Ws0, Wn0, Wb0, Ws1, Wn1, Wb1, Ws2, Wn2, Wb2);
    // CSR pass B (+ nb histogram) fused with layer-0 GEMM
    k_binBg0<<<NBKT + NBLK_GEMM, 256, 0, stream>>>(pairs, gcur, row_ptr, deg_inv, edge_src, nbins,
                                                   x, Wb0, b0, zsA, znA);
    // degree-sorted permutation
    k_scan<<<1, 64, 0, stream>>>(nbins, ncur);
    k_mkperm<<<(NNODES + 255) / 256, 256, 0, stream>>>(row_ptr, ncur, perm);
    // agg layer 0 + GEMM layer 1 (fused; no h1 roundtrip)
    k_aggemm<128><<<NNODES / 16, 256, 0, stream>>>(znA, zsA, row_ptr, edge_src, deg_inv, perm,
                                                   Wb1, b1, zsB, znB);
    // agg layer 1 + GEMM layer 2 (fused; no h2 roundtrip)
    k_aggemm<64><<<NNODES / 16, 256, 0, stream>>>(znB, zsB, row_ptr, edge_src, deg_inv, perm,
                                                  Wb2, b2, zs32, zn64);
    // final agg layer 2 -> out (f32)
    k_aggfin<<<NNODES / 32, 256, 0, stream>>>(zn64, zs32, row_ptr, edge_src, deg_inv, perm, out);
}